// Round 5
// baseline (16405.542 us; speedup 1.0000x reference)
//
#include <hip/hip_runtime.h>

typedef unsigned short ushort_t;
typedef unsigned long long u64_t;
typedef __attribute__((ext_vector_type(8))) short short8;
typedef __attribute__((ext_vector_type(4))) float floatx4;

// Problem constants: V=50000, E=512, H=512, L=32, B=64, T=512
// Chunked: NC=8 chunks of CS=64 steps.

__device__ __forceinline__ float bf2f(ushort_t u) {
  unsigned x = ((unsigned)u) << 16;
  return __builtin_bit_cast(float, x);
}
__device__ __forceinline__ ushort_t f2bf(float f) {
  unsigned x = __builtin_bit_cast(unsigned, f);
  x += 0x7FFFu + ((x >> 16) & 1u);
  return (ushort_t)(x >> 16);
}
__device__ __forceinline__ float sigf(float x) { return 1.0f / (1.0f + __expf(-x)); }
__device__ __forceinline__ float tanhf_(float x) { return 1.0f - 2.0f / (__expf(2.0f * x) + 1.0f); }

// ---------------- workspace layout (bytes) ----------------
static const size_t OFF_A    = 0;            // union: x_bf [32768][512] bf16 | out1 [32768][1024] bf16
static const size_t OFF_OUT0 = 67108864;     // out0 [32768][1024] bf16
static const size_t OFF_XG   = 134217728;    // xg0c+xg1c [64][64][2048] bf16 each; emis f32 aliases
static const size_t OFF_WIH0 = 167772160;    // wih0_bf
static const size_t OFF_WIH1 = 171966464;    // wih1_bf
static const size_t OFF_BIAS = 180355072;    // bias [2][2][2048] f32
static const size_t OFF_WOUT = 180387840;    // w_out frag-major bf16
static const size_t OFF_HC   = 180453376;    // h exchange [2 layer][2 dir][2 parity][32768] u32 (tagged) 1 MiB
static const size_t OFF_CST  = 181501952;    // c state [2 layer][2 dir][64][512] f32  524288
static const size_t OFF_NUM  = 182026240;    // num[64] f32
static const size_t OFF_PERB = 182026496;    // perb[64] f32
static const size_t OFF_END  = 182026752;

// ---------------- prep ----------------
__global__ void prep_kernel(const float* __restrict__ w_ih0, const float* __restrict__ w_ih1,
                            const float* __restrict__ b_ih, const float* __restrict__ b_hh,
                            const float* __restrict__ w_out,
                            ushort_t* __restrict__ wih0_bf, ushort_t* __restrict__ wih1_bf,
                            float* __restrict__ bias, ushort_t* __restrict__ wout_bf) {
  int idx = blockIdx.x * 256 + threadIdx.x;
  int stride = gridDim.x * 256;
  for (int i = idx; i < 2097152; i += stride) wih0_bf[i] = f2bf(w_ih0[i]);
  for (int i = idx; i < 4194304; i += stride) wih1_bf[i] = f2bf(w_ih1[i]);
  for (int i = idx; i < 8192; i += stride) bias[i] = b_ih[i] + b_hh[i];
  for (int i = idx; i < 32768; i += stride) {
    int j = i & 7, Ls = (i >> 3) & 63, kb = (i >> 9) & 31, nt = i >> 14;
    int n = nt * 16 + (Ls & 15);
    int k = kb * 32 + ((Ls >> 4) & 3) * 8 + j;
    wout_bf[i] = f2bf(w_out[k * 32 + n]);
  }
}

// ---------------- embedding gather + cast ----------------
__global__ void embed_kernel(const int* __restrict__ datas, const float* __restrict__ emb,
                             ushort_t* __restrict__ x_bf) {
  int idx = blockIdx.x * 256 + threadIdx.x;  // < 2097152
  int row = idx >> 6, sub = idx & 63;
  int tok = datas[row];
  const float4* ep = (const float4*)(emb + (size_t)tok * 512 + sub * 8);
  float4 f0 = ep[0], f1 = ep[1];
  short8 v;
  v[0] = (short)f2bf(f0.x); v[1] = (short)f2bf(f0.y);
  v[2] = (short)f2bf(f0.z); v[3] = (short)f2bf(f0.w);
  v[4] = (short)f2bf(f1.x); v[5] = (short)f2bf(f1.y);
  v[6] = (short)f2bf(f1.z); v[7] = (short)f2bf(f1.w);
  *(short8*)(x_bf + (size_t)row * 512 + sub * 8) = v;
}

// ---------------- chunked input-projection GEMM (unchanged) ----------------
__global__ __launch_bounds__(256) void gemm_chunk(const ushort_t* __restrict__ A, int K,
                                                  const ushort_t* __restrict__ W,
                                                  const float* __restrict__ biasL,
                                                  ushort_t* __restrict__ xg0c,
                                                  ushort_t* __restrict__ xg1c,
                                                  int t00, int t01) {
  __shared__ alignas(16) ushort_t alds[512 * 8];
  __shared__ alignas(16) ushort_t blds[512 * 8];
  int gid = blockIdx.x;
  int dir = gid >> 9, r = gid & 511;
  int mt = r & 31, ntt = r >> 5;
  int t0 = dir ? t01 : t00;
  const ushort_t* Bm = W + (size_t)dir * 2048 * K;
  const float* bptr = biasL + dir * 2048;
  ushort_t* xg = dir ? xg1c : xg0c;
  int bm0 = mt * 128, bn0 = ntt * 128;
  int tid = threadIdx.x, L = tid & 63, w = tid >> 6;
  int wm = w & 1, wn = w >> 1;
  floatx4 acc[4][4] = {};
  for (int k0 = 0; k0 < K; k0 += 32) {
    __syncthreads();
    #pragma unroll
    for (int rep = 0; rep < 2; rep++) {
      int slot = rep * 256 + tid;
      int t8 = slot >> 6, Ls = slot & 63;
      int col = k0 + (Ls >> 4) * 8;
      int mp = bm0 + t8 * 16 + (Ls & 15);
      int Arow = (mp >> 6) * 512 + t0 + (mp & 63);
      *(short8*)&alds[slot * 8] = *(const short8*)&A[(size_t)Arow * K + col];
      int rowb = bn0 + t8 * 16 + (Ls & 15);
      *(short8*)&blds[slot * 8] = *(const short8*)&Bm[(size_t)rowb * K + col];
    }
    __syncthreads();
    short8 af[4];
    #pragma unroll
    for (int a = 0; a < 4; a++) af[a] = *(const short8*)&alds[((wm * 4 + a) * 64 + L) * 8];
    #pragma unroll
    for (int bq = 0; bq < 4; bq++) {
      short8 bfr = *(const short8*)&blds[((wn * 4 + bq) * 64 + L) * 8];
      #pragma unroll
      for (int a = 0; a < 4; a++)
        acc[a][bq] = __builtin_amdgcn_mfma_f32_16x16x32_bf16(af[a], bfr, acc[a][bq], 0, 0, 0);
    }
  }
  int lm = L >> 4, ln = L & 15;
  #pragma unroll
  for (int bq = 0; bq < 4; bq++) {
    int n = bn0 + (wn * 4 + bq) * 16 + ln;
    float bv = bptr[n];
    #pragma unroll
    for (int a = 0; a < 4; a++) {
      #pragma unroll
      for (int rr = 0; rr < 4; rr++) {
        int m = bm0 + (wm * 4 + a) * 16 + lm * 4 + rr;
        int b = m >> 6, ts = m & 63;
        xg[((size_t)(ts * 64 + b)) * 2048 + n] = f2bf(acc[a][bq][rr] + bv);
      }
    }
  }
}

// ---------------- recurrent LSTM, tag-in-data exchange (no barriers, no fences) ----------------
// h word for (m, khid) in buffer[parity]: windex = ((m>>4)*16 + (khid>>5))*512
//   + ((khid>>3)&3)*128 + (m&15)*8 + (khid&7); word = (bf16<<16) | step_tag.
// Consumer at global step s reads buf[s&1], target tag s. Producer stores tag s+1 into buf[(s+1)&1].
// Parity + monotonic tags make overwrite-before-read impossible; per-dword store atomicity
// makes torn lines detectable. No __syncthreads in the step loop: waves free-run.
__global__ __launch_bounds__(256, 1) void lstm_chunk(const ushort_t* __restrict__ xg0c,
                                                     const ushort_t* __restrict__ xg1c,
                                                     const float* __restrict__ whh_f,
                                                     unsigned* __restrict__ hcL,   // [2 dir][2 parity][32768] u32
                                                     float* __restrict__ cstL,     // [2 dir][64][512]
                                                     ushort_t* __restrict__ outL,  // [32768][1024]
                                                     int c) {
  __shared__ alignas(16) ushort_t wlds[32768];  // 64 KB, B-frag-major Whh slice (bf16)
  int bid = blockIdx.x, d = bid >> 5, g = bid & 31, j0 = g * 16;
  int tid = threadIdx.x, L = tid & 63, w = tid >> 6;
  const float* wptr = whh_f + (size_t)d * 2048 * 512;
  #pragma unroll
  for (int it = 0; it < 16; it++) {
    int slot = it * 256 + tid;  // 0..4095
    int qg = slot >> 10, kb = (slot >> 6) & 15, Ls = slot & 63;
    int gcol = qg * 512 + j0 + (Ls & 15);
    int k = kb * 32 + (Ls >> 4) * 8;
    const float* src = wptr + (size_t)gcol * 512 + k;
    float4 f0 = *(const float4*)src;
    float4 f1 = *(const float4*)(src + 4);
    short8 v;
    v[0] = (short)f2bf(f0.x); v[1] = (short)f2bf(f0.y);
    v[2] = (short)f2bf(f0.z); v[3] = (short)f2bf(f0.w);
    v[4] = (short)f2bf(f1.x); v[5] = (short)f2bf(f1.y);
    v[6] = (short)f2bf(f1.z); v[7] = (short)f2bf(f1.w);
    *(short8*)&wlds[slot * 8] = v;
  }
  __syncthreads();
  const ushort_t* xgd = d ? xg1c : xg0c;
  unsigned* hcd = hcL + (size_t)d * 2 * 32768;
  int q8 = L >> 4, jj = L & 15;
  int mbase = w * 16 + q8 * 4;                 // C-layout batch-row base
  int rb = w * 16 * 256 + q8 * 64 + jj * 4;    // reader u64 base; + kb*256 + qq
  int wb = (w * 16 + (g >> 1)) * 512 + ((g & 1) * 2 + (jj >> 3)) * 128 + q8 * 32 + (jj & 7);
  const u64_t TMASK = 0x0000FFFF0000FFFFull;
  float cv[4];
  #pragma unroll
  for (int rr = 0; rr < 4; rr++) cv[rr] = cstL[(size_t)d * 32768 + (mbase + rr) * 512 + j0 + jj];

  for (int sl = 0; sl < 64; sl++) {
    int s = c * 64 + sl;
    int t = d ? (511 - s) : s;
    int ts = d ? (63 - sl) : sl;
    const u64_t* h64 = (const u64_t*)(hcd + (size_t)(s & 1) * 32768);
    unsigned* hw = hcd + (size_t)((s + 1) & 1) * 32768;
    u64_t tag2 = ((u64_t)(unsigned)s) | ((u64_t)(unsigned)s << 32);
    // ---- issue all 64 h loads (independent, one RTT) ----
    u64_t hv[64];
    #pragma unroll
    for (int kb = 0; kb < 16; kb++) {
      #pragma unroll
      for (int qq = 0; qq < 4; qq++)
        hv[kb * 4 + qq] = __hip_atomic_load(h64 + rb + kb * 256 + qq,
                                            __ATOMIC_RELAXED, __HIP_MEMORY_SCOPE_SYSTEM);
    }
    // ---- xg loads for this step (consumed after MFMA; overlap the poll) ----
    ushort_t xgu[4][4];
    #pragma unroll
    for (int rr = 0; rr < 4; rr++) {
      const ushort_t* xrow = xgd + ((size_t)(ts * 64 + mbase + rr)) * 2048 + j0 + jj;
      #pragma unroll
      for (int qg = 0; qg < 4; qg++) xgu[qg][rr] = xrow[qg * 512];
    }
    // ---- tag check + re-poll only missing words ----
    u64_t pend = 0;
    #pragma unroll
    for (int i = 0; i < 64; i++)
      if (((hv[i] ^ tag2) & TMASK) != 0) pend |= (1ull << i);
    int guard = 0;
    while (pend != 0 && guard < (1 << 20)) {
      #pragma unroll
      for (int i = 0; i < 64; i++) {
        if ((pend >> i) & 1) {
          u64_t v = __hip_atomic_load(h64 + rb + (i >> 2) * 256 + (i & 3),
                                      __ATOMIC_RELAXED, __HIP_MEMORY_SCOPE_SYSTEM);
          if (((v ^ tag2) & TMASK) == 0) { hv[i] = v; pend &= ~(1ull << i); }
        }
      }
      guard++;
    }
    // ---- repack + MFMA ----
    floatx4 acc[4] = {};
    #pragma unroll
    for (int kb = 0; kb < 16; kb++) {
      union { unsigned u[4]; short8 v8; } af;
      #pragma unroll
      for (int qq = 0; qq < 4; qq++) {
        u64_t h = hv[kb * 4 + qq];
        af.u[qq] = (unsigned)((h >> 16) & 0xffffu) | (unsigned)((h >> 32) & 0xffff0000u);
      }
      #pragma unroll
      for (int qg = 0; qg < 4; qg++) {
        short8 bfr = *(const short8*)&wlds[((qg * 16 + kb) * 64 + L) * 8];
        acc[qg] = __builtin_amdgcn_mfma_f32_16x16x32_bf16(af.v8, bfr, acc[qg], 0, 0, 0);
      }
    }
    // ---- pointwise LSTM cell ----
    ushort_t hbv[4];
    #pragma unroll
    for (int rr = 0; rr < 4; rr++) {
      float ii = acc[0][rr] + bf2f(xgu[0][rr]);
      float ff = acc[1][rr] + bf2f(xgu[1][rr]);
      float gg = acc[2][rr] + bf2f(xgu[2][rr]);
      float oo = acc[3][rr] + bf2f(xgu[3][rr]);
      float cc = sigf(ff) * cv[rr] + sigf(ii) * tanhf_(gg);
      cv[rr] = cc;
      hbv[rr] = f2bf(sigf(oo) * tanhf_(cc));
    }
    // ---- store tagged h (fire-and-forget) + out ----
    unsigned tagw = (unsigned)(s + 1) & 0xffffu;
    #pragma unroll
    for (int rr = 0; rr < 4; rr++)
      __hip_atomic_store(hw + wb + rr * 8, ((unsigned)hbv[rr] << 16) | tagw,
                         __ATOMIC_RELAXED, __HIP_MEMORY_SCOPE_SYSTEM);
    bool evn = (jj & 1) == 0;
    #pragma unroll
    for (int rr = 0; rr < 4; rr++) {
      unsigned mine = (unsigned)hbv[rr];
      unsigned nb = (unsigned)__shfl_xor((int)mine, 1, 64);
      if (evn) {
        unsigned packed = mine | (nb << 16);
        int m = mbase + rr;
        *(unsigned*)&outL[((size_t)m * 512 + t) * 1024 + (d << 9) + j0 + jj] = packed;
      }
    }
  }
  #pragma unroll
  for (int rr = 0; rr < 4; rr++) cstL[(size_t)d * 32768 + (mbase + rr) * 512 + j0 + jj] = cv[rr];
}

// ---------------- emissions ----------------
__global__ __launch_bounds__(256) void emis_kernel(const ushort_t* __restrict__ out1,
                                                   const ushort_t* __restrict__ wout_bf,
                                                   const float* __restrict__ b_out,
                                                   float* __restrict__ emis) {
  int tid = threadIdx.x, L = tid & 63, w = tid >> 6;
  int bm0 = blockIdx.x * 128;
  int q8 = L >> 4, ln = L & 15;
  floatx4 acc[2][2] = {};
  #pragma unroll 4
  for (int kb = 0; kb < 32; kb++) {
    short8 a0 = *(const short8*)&out1[(size_t)(bm0 + (w * 2 + 0) * 16 + ln) * 1024 + kb * 32 + q8 * 8];
    short8 a1 = *(const short8*)&out1[(size_t)(bm0 + (w * 2 + 1) * 16 + ln) * 1024 + kb * 32 + q8 * 8];
    #pragma unroll
    for (int nt = 0; nt < 2; nt++) {
      short8 bfr = *(const short8*)&wout_bf[((size_t)(nt * 32 + kb) * 64 + L) * 8];
      acc[0][nt] = __builtin_amdgcn_mfma_f32_16x16x32_bf16(a0, bfr, acc[0][nt], 0, 0, 0);
      acc[1][nt] = __builtin_amdgcn_mfma_f32_16x16x32_bf16(a1, bfr, acc[1][nt], 0, 0, 0);
    }
  }
  #pragma unroll
  for (int mt = 0; mt < 2; mt++) {
    #pragma unroll
    for (int nt = 0; nt < 2; nt++) {
      int n = nt * 16 + ln;
      float bv = b_out[n];
      #pragma unroll
      for (int rr = 0; rr < 4; rr++) {
        int m = bm0 + (w * 2 + mt) * 16 + q8 * 4 + rr;
        emis[(size_t)m * 32 + n] = acc[mt][nt][rr] + bv;
      }
    }
  }
}

// ---------------- CRF numerator ----------------
__global__ void num_kernel(const int* __restrict__ labels, const float* __restrict__ emis,
                           const float* __restrict__ trans, const float* __restrict__ cstart,
                           const float* __restrict__ cend, float* __restrict__ num) {
  int b = blockIdx.x, tid = threadIdx.x;
  float s = 0.f;
  for (int t = tid; t < 512; t += 64) {
    int tag = labels[b * 512 + t];
    s += emis[(size_t)(b * 512 + t) * 32 + tag];
    if (t < 511) s += trans[tag * 32 + labels[b * 512 + t + 1]];
  }
  #pragma unroll
  for (int off = 32; off > 0; off >>= 1) s += __shfl_xor(s, off, 64);
  if (tid == 0) num[b] = s + cstart[labels[b * 512]] + cend[labels[b * 512 + 511]];
}

// ---------------- CRF forward scan: linear-space inner product, one exp+log per step ----------------
__global__ __launch_bounds__(64) void fwd_kernel(const float* __restrict__ emis,
                                                 const float* __restrict__ trans,
                                                 const float* __restrict__ cstart,
                                                 const float* __restrict__ cend,
                                                 const float* __restrict__ num,
                                                 float* __restrict__ perb) {
  int b = blockIdx.x, tid = threadIdx.x, j = tid & 31;
  float Pj[32];
  #pragma unroll
  for (int i = 0; i < 32; i++) Pj[i] = __expf(trans[i * 32 + j]);
  float alpha = cstart[j] + emis[(size_t)(b * 512) * 32 + j];
  for (int t = 1; t < 512; t++) {
    float e = emis[(size_t)(b * 512 + t) * 32 + j];  // overlaps the reductions below
    float M = alpha;
    #pragma unroll
    for (int off = 16; off > 0; off >>= 1) M = fmaxf(M, __shfl_xor(M, off, 32));
    float A = __expf(alpha - M);
    float s0 = 0.f, s1 = 0.f, s2 = 0.f, s3 = 0.f;
    #pragma unroll
    for (int i = 0; i < 32; i += 4) {
      s0 += __shfl(A, i, 32) * Pj[i];
      s1 += __shfl(A, i + 1, 32) * Pj[i + 1];
      s2 += __shfl(A, i + 2, 32) * Pj[i + 2];
      s3 += __shfl(A, i + 3, 32) * Pj[i + 3];
    }
    alpha = __logf((s0 + s1) + (s2 + s3)) + M + e;
  }
  float z = alpha + cend[j];
  float m2 = z;
  #pragma unroll
  for (int off = 16; off > 0; off >>= 1) m2 = fmaxf(m2, __shfl_xor(m2, off, 32));
  float s2 = __expf(z - m2);
  #pragma unroll
  for (int off = 16; off > 0; off >>= 1) s2 += __shfl_xor(s2, off, 32);
  if (tid == 0) perb[b] = num[b] - (__logf(s2) + m2);
}

__global__ void final_kernel(const float* __restrict__ perb, float* __restrict__ out) {
  int tid = threadIdx.x;
  float s = perb[tid];
  #pragma unroll
  for (int off = 32; off > 0; off >>= 1) s += __shfl_xor(s, off, 64);
  if (tid == 0) out[0] = -s;
}

// ---------------- host launch ----------------
extern "C" void kernel_launch(void* const* d_in, const int* in_sizes, int n_in,
                              void* d_out, int out_size, void* d_ws, size_t ws_size,
                              hipStream_t stream) {
  (void)in_sizes; (void)n_in; (void)out_size; (void)ws_size;
  const int* datas = (const int*)d_in[0];
  const int* labels = (const int*)d_in[1];
  const float* emb = (const float*)d_in[2];
  const float* w_ih0 = (const float*)d_in[3];
  const float* w_ih1 = (const float*)d_in[4];
  const float* w_hh = (const float*)d_in[5];
  const float* b_ih = (const float*)d_in[6];
  const float* b_hh = (const float*)d_in[7];
  const float* w_out = (const float*)d_in[8];
  const float* b_out = (const float*)d_in[9];
  const float* cstart = (const float*)d_in[10];
  const float* cend = (const float*)d_in[11];
  const float* ctrans = (const float*)d_in[12];

  char* ws = (char*)d_ws;
  ushort_t* x_bf = (ushort_t*)(ws + OFF_A);
  ushort_t* out1 = (ushort_t*)(ws + OFF_A);
  ushort_t* out0 = (ushort_t*)(ws + OFF_OUT0);
  ushort_t* xg0c = (ushort_t*)(ws + OFF_XG);
  ushort_t* xg1c = (ushort_t*)(ws + OFF_XG + 16777216);
  float* emis = (float*)(ws + OFF_XG);
  ushort_t* wih0_bf = (ushort_t*)(ws + OFF_WIH0);
  ushort_t* wih1_bf = (ushort_t*)(ws + OFF_WIH1);
  float* bias = (float*)(ws + OFF_BIAS);
  ushort_t* wout_bf = (ushort_t*)(ws + OFF_WOUT);
  unsigned* hc0 = (unsigned*)(ws + OFF_HC);   // layer0: [2 dir][2 parity][32768] u32
  unsigned* hc1 = hc0 + 131072;               // layer1
  float* cst0 = (float*)(ws + OFF_CST);
  float* cst1 = cst0 + 65536;
  float* numb = (float*)(ws + OFF_NUM);
  float* perb = (float*)(ws + OFF_PERB);

  // zero tagged h buffers (tag 0 = step-0 zeros), carry state, num/perb
  hipMemsetAsync(ws + OFF_HC, 0, OFF_END - OFF_HC, stream);

  prep_kernel<<<2048, 256, 0, stream>>>(w_ih0, w_ih1, b_ih, b_hh, w_out,
                                        wih0_bf, wih1_bf, bias, wout_bf);
  embed_kernel<<<8192, 256, 0, stream>>>(datas, emb, x_bf);

  // layer 0 (A = x_bf, K=512)
  for (int c = 0; c < 8; c++) {
    gemm_chunk<<<1024, 256, 0, stream>>>(x_bf, 512, wih0_bf, bias, xg0c, xg1c,
                                         c * 64, (7 - c) * 64);
    lstm_chunk<<<64, 256, 0, stream>>>(xg0c, xg1c, w_hh, hc0, cst0, out0, c);
  }
  // layer 1 (A = out0, K=1024)
  for (int c = 0; c < 8; c++) {
    gemm_chunk<<<1024, 256, 0, stream>>>(out0, 1024, wih1_bf, bias + 4096, xg0c, xg1c,
                                         c * 64, (7 - c) * 64);
    lstm_chunk<<<64, 256, 0, stream>>>(xg0c, xg1c, w_hh + 2097152, hc1, cst1, out1, c);
  }

  // emissions + CRF
  emis_kernel<<<256, 256, 0, stream>>>(out1, wout_bf, b_out, emis);
  num_kernel<<<64, 64, 0, stream>>>(labels, emis, ctrans, cstart, cend, numb);
  fwd_kernel<<<64, 64, 0, stream>>>(emis, ctrans, cstart, cend, numb, perb);
  final_kernel<<<1, 64, 0, stream>>>(perb, (float*)d_out);
}

// Round 6
// 10209.941 us; speedup vs baseline: 1.6068x; 1.6068x over previous
//
#include <hip/hip_runtime.h>

typedef unsigned short ushort_t;
typedef unsigned long long u64_t;
typedef __attribute__((ext_vector_type(8))) short short8;
typedef __attribute__((ext_vector_type(4))) float floatx4;

// Problem constants: V=50000, E=512, H=512, L=32, B=64, T=512
// Chunked: NC=8 chunks of CS=64 steps.

__device__ __forceinline__ float bf2f(ushort_t u) {
  unsigned x = ((unsigned)u) << 16;
  return __builtin_bit_cast(float, x);
}
__device__ __forceinline__ ushort_t f2bf(float f) {
  unsigned x = __builtin_bit_cast(unsigned, f);
  x += 0x7FFFu + ((x >> 16) & 1u);
  return (ushort_t)(x >> 16);
}
__device__ __forceinline__ float sigf(float x) { return 1.0f / (1.0f + __expf(-x)); }
__device__ __forceinline__ float tanhf_(float x) { return 1.0f - 2.0f / (__expf(2.0f * x) + 1.0f); }

// ---------------- workspace layout (bytes) ----------------
static const size_t OFF_A    = 0;            // union: x_bf [32768][512] bf16 | out1 [32768][1024] bf16
static const size_t OFF_OUT0 = 67108864;     // out0 [32768][1024] bf16
static const size_t OFF_XG   = 134217728;    // xg0c+xg1c [64][64][2048] bf16 each; emis f32 aliases
static const size_t OFF_WIH0 = 167772160;    // wih0_bf
static const size_t OFF_WIH1 = 171966464;    // wih1_bf
static const size_t OFF_BIAS = 180355072;    // bias [2][2][2048] f32
static const size_t OFF_WOUT = 180387840;    // w_out frag-major bf16
static const size_t OFF_HC   = 180453376;    // h exchange [2 layer][2 dir][2 parity][32768] u32 (tagged) 1 MiB
static const size_t OFF_CST  = 181501952;    // c state [2 layer][2 dir][64][512] f32  524288
static const size_t OFF_NUM  = 182026240;    // num[64] f32
static const size_t OFF_PERB = 182026496;    // perb[64] f32
static const size_t OFF_END  = 182026752;

// ---------------- prep ----------------
__global__ void prep_kernel(const float* __restrict__ w_ih0, const float* __restrict__ w_ih1,
                            const float* __restrict__ b_ih, const float* __restrict__ b_hh,
                            const float* __restrict__ w_out,
                            ushort_t* __restrict__ wih0_bf, ushort_t* __restrict__ wih1_bf,
                            float* __restrict__ bias, ushort_t* __restrict__ wout_bf) {
  int idx = blockIdx.x * 256 + threadIdx.x;
  int stride = gridDim.x * 256;
  for (int i = idx; i < 2097152; i += stride) wih0_bf[i] = f2bf(w_ih0[i]);
  for (int i = idx; i < 4194304; i += stride) wih1_bf[i] = f2bf(w_ih1[i]);
  for (int i = idx; i < 8192; i += stride) bias[i] = b_ih[i] + b_hh[i];
  for (int i = idx; i < 32768; i += stride) {
    int j = i & 7, Ls = (i >> 3) & 63, kb = (i >> 9) & 31, nt = i >> 14;
    int n = nt * 16 + (Ls & 15);
    int k = kb * 32 + ((Ls >> 4) & 3) * 8 + j;
    wout_bf[i] = f2bf(w_out[k * 32 + n]);
  }
}

// ---------------- embedding gather + cast ----------------
__global__ void embed_kernel(const int* __restrict__ datas, const float* __restrict__ emb,
                             ushort_t* __restrict__ x_bf) {
  int idx = blockIdx.x * 256 + threadIdx.x;  // < 2097152
  int row = idx >> 6, sub = idx & 63;
  int tok = datas[row];
  const float4* ep = (const float4*)(emb + (size_t)tok * 512 + sub * 8);
  float4 f0 = ep[0], f1 = ep[1];
  short8 v;
  v[0] = (short)f2bf(f0.x); v[1] = (short)f2bf(f0.y);
  v[2] = (short)f2bf(f0.z); v[3] = (short)f2bf(f0.w);
  v[4] = (short)f2bf(f1.x); v[5] = (short)f2bf(f1.y);
  v[6] = (short)f2bf(f1.z); v[7] = (short)f2bf(f1.w);
  *(short8*)(x_bf + (size_t)row * 512 + sub * 8) = v;
}

// ---------------- chunked input-projection GEMM (unchanged) ----------------
__global__ __launch_bounds__(256) void gemm_chunk(const ushort_t* __restrict__ A, int K,
                                                  const ushort_t* __restrict__ W,
                                                  const float* __restrict__ biasL,
                                                  ushort_t* __restrict__ xg0c,
                                                  ushort_t* __restrict__ xg1c,
                                                  int t00, int t01) {
  __shared__ alignas(16) ushort_t alds[512 * 8];
  __shared__ alignas(16) ushort_t blds[512 * 8];
  int gid = blockIdx.x;
  int dir = gid >> 9, r = gid & 511;
  int mt = r & 31, ntt = r >> 5;
  int t0 = dir ? t01 : t00;
  const ushort_t* Bm = W + (size_t)dir * 2048 * K;
  const float* bptr = biasL + dir * 2048;
  ushort_t* xg = dir ? xg1c : xg0c;
  int bm0 = mt * 128, bn0 = ntt * 128;
  int tid = threadIdx.x, L = tid & 63, w = tid >> 6;
  int wm = w & 1, wn = w >> 1;
  floatx4 acc[4][4] = {};
  for (int k0 = 0; k0 < K; k0 += 32) {
    __syncthreads();
    #pragma unroll
    for (int rep = 0; rep < 2; rep++) {
      int slot = rep * 256 + tid;
      int t8 = slot >> 6, Ls = slot & 63;
      int col = k0 + (Ls >> 4) * 8;
      int mp = bm0 + t8 * 16 + (Ls & 15);
      int Arow = (mp >> 6) * 512 + t0 + (mp & 63);
      *(short8*)&alds[slot * 8] = *(const short8*)&A[(size_t)Arow * K + col];
      int rowb = bn0 + t8 * 16 + (Ls & 15);
      *(short8*)&blds[slot * 8] = *(const short8*)&Bm[(size_t)rowb * K + col];
    }
    __syncthreads();
    short8 af[4];
    #pragma unroll
    for (int a = 0; a < 4; a++) af[a] = *(const short8*)&alds[((wm * 4 + a) * 64 + L) * 8];
    #pragma unroll
    for (int bq = 0; bq < 4; bq++) {
      short8 bfr = *(const short8*)&blds[((wn * 4 + bq) * 64 + L) * 8];
      #pragma unroll
      for (int a = 0; a < 4; a++)
        acc[a][bq] = __builtin_amdgcn_mfma_f32_16x16x32_bf16(af[a], bfr, acc[a][bq], 0, 0, 0);
    }
  }
  int lm = L >> 4, ln = L & 15;
  #pragma unroll
  for (int bq = 0; bq < 4; bq++) {
    int n = bn0 + (wn * 4 + bq) * 16 + ln;
    float bv = bptr[n];
    #pragma unroll
    for (int a = 0; a < 4; a++) {
      #pragma unroll
      for (int rr = 0; rr < 4; rr++) {
        int m = bm0 + (wm * 4 + a) * 16 + lm * 4 + rr;
        int b = m >> 6, ts = m & 63;
        xg[((size_t)(ts * 64 + b)) * 2048 + n] = f2bf(acc[a][bq][rr] + bv);
      }
    }
  }
}

// ---------------- recurrent LSTM, tag-in-data exchange (no barriers, no fences) ----------------
// h word for (m, khid) in buffer[parity]: windex = ((m>>4)*16 + (khid>>5))*512
//   + ((khid>>3)&3)*128 + (m&15)*8 + (khid&7); word = (bf16<<16) | step_tag.
// Consumer at step s reads buf[s&1] expecting tag s; producer stores tag s+1 into buf[(s+1)&1].
// Poll protocol: BULK re-issue of all 64 u64 loads per round (one RTT), then a non-divergent
// OR-reduce tag check. No per-word retry, no long-lived pending mask.
__global__ __launch_bounds__(256, 1) void lstm_chunk(const ushort_t* __restrict__ xg0c,
                                                     const ushort_t* __restrict__ xg1c,
                                                     const float* __restrict__ whh_f,
                                                     unsigned* __restrict__ hcL,   // [2 dir][2 parity][32768] u32
                                                     float* __restrict__ cstL,     // [2 dir][64][512]
                                                     ushort_t* __restrict__ outL,  // [32768][1024]
                                                     int c) {
  __shared__ alignas(16) ushort_t wlds[32768];  // 64 KB, B-frag-major Whh slice (bf16)
  int bid = blockIdx.x, d = bid >> 5, g = bid & 31, j0 = g * 16;
  int tid = threadIdx.x, L = tid & 63, w = tid >> 6;
  const float* wptr = whh_f + (size_t)d * 2048 * 512;
  #pragma unroll
  for (int it = 0; it < 16; it++) {
    int slot = it * 256 + tid;  // 0..4095
    int qg = slot >> 10, kb = (slot >> 6) & 15, Ls = slot & 63;
    int gcol = qg * 512 + j0 + (Ls & 15);
    int k = kb * 32 + (Ls >> 4) * 8;
    const float* src = wptr + (size_t)gcol * 512 + k;
    float4 f0 = *(const float4*)src;
    float4 f1 = *(const float4*)(src + 4);
    short8 v;
    v[0] = (short)f2bf(f0.x); v[1] = (short)f2bf(f0.y);
    v[2] = (short)f2bf(f0.z); v[3] = (short)f2bf(f0.w);
    v[4] = (short)f2bf(f1.x); v[5] = (short)f2bf(f1.y);
    v[6] = (short)f2bf(f1.z); v[7] = (short)f2bf(f1.w);
    *(short8*)&wlds[slot * 8] = v;
  }
  __syncthreads();
  const ushort_t* xgd = d ? xg1c : xg0c;
  unsigned* hcd = hcL + (size_t)d * 2 * 32768;
  int q8 = L >> 4, jj = L & 15;
  int mbase = w * 16 + q8 * 4;                 // C-layout batch-row base
  int rb = w * 16 * 256 + q8 * 64 + jj * 4;    // reader u64 base; + kb*256 + qq
  int wb = (w * 16 + (g >> 1)) * 512 + ((g & 1) * 2 + (jj >> 3)) * 128 + q8 * 32 + (jj & 7);
  const u64_t TMASK = 0x0000FFFF0000FFFFull;
  float cv[4];
  #pragma unroll
  for (int rr = 0; rr < 4; rr++) cv[rr] = cstL[(size_t)d * 32768 + (mbase + rr) * 512 + j0 + jj];

  auto ldxg = [&](int sl2, ushort_t dst[4][4]) {
    int ts2 = d ? (63 - sl2) : sl2;
    #pragma unroll
    for (int rr = 0; rr < 4; rr++) {
      const ushort_t* xrow = xgd + ((size_t)(ts2 * 64 + mbase + rr)) * 2048 + j0 + jj;
      #pragma unroll
      for (int qg = 0; qg < 4; qg++) dst[qg][rr] = xrow[qg * 512];
    }
  };

  ushort_t xgu[4][4];
  ldxg(0, xgu);  // xg for step 0 (waited at first use)

  for (int sl = 0; sl < 64; sl++) {
    int s = c * 64 + sl;
    int t = d ? (511 - s) : s;
    const u64_t* h64 = (const u64_t*)(hcd + (size_t)(s & 1) * 32768);
    unsigned* hw = hcd + (size_t)((s + 1) & 1) * 32768;
    u64_t tag2 = ((u64_t)(unsigned)(s & 0xffff)) | ((u64_t)(unsigned)(s & 0xffff) << 32);
    u64_t hv[64];
    // bulk issue: all 64 h loads first (in-order vmcnt => waiting on h never waits on xg)
    #pragma unroll
    for (int i = 0; i < 64; i++)
      hv[i] = __hip_atomic_load(h64 + rb + (i >> 2) * 256 + (i & 3),
                                __ATOMIC_RELAXED, __HIP_MEMORY_SCOPE_SYSTEM);
    // prefetch next step's xg (retired during compute; never explicitly drained)
    ushort_t xgn[4][4];
    if (sl < 63) ldxg(sl + 1, xgn);
    // ---- poll: re-issue ALL loads per round; non-divergent OR-reduce tag check ----
    int guard = 0;
    while (true) {
      u64_t bad = 0;
      #pragma unroll
      for (int i = 0; i < 64; i++) bad |= (hv[i] ^ tag2) & TMASK;
      if (bad == 0) break;
      if (++guard >= (1 << 15)) break;
      #pragma unroll
      for (int i = 0; i < 64; i++)
        hv[i] = __hip_atomic_load(h64 + rb + (i >> 2) * 256 + (i & 3),
                                  __ATOMIC_RELAXED, __HIP_MEMORY_SCOPE_SYSTEM);
    }
    // ---- repack + MFMA ----
    floatx4 acc[4] = {};
    #pragma unroll
    for (int kb = 0; kb < 16; kb++) {
      union { unsigned u[4]; short8 v8; } af;
      #pragma unroll
      for (int qq = 0; qq < 4; qq++) {
        u64_t h = hv[kb * 4 + qq];
        af.u[qq] = (unsigned)((h >> 16) & 0xffffu) | (unsigned)((h >> 32) & 0xffff0000u);
      }
      #pragma unroll
      for (int qg = 0; qg < 4; qg++) {
        short8 bfr = *(const short8*)&wlds[((qg * 16 + kb) * 64 + L) * 8];
        acc[qg] = __builtin_amdgcn_mfma_f32_16x16x32_bf16(af.v8, bfr, acc[qg], 0, 0, 0);
      }
    }
    // ---- pointwise LSTM cell ----
    ushort_t hbv[4];
    #pragma unroll
    for (int rr = 0; rr < 4; rr++) {
      float ii = acc[0][rr] + bf2f(xgu[0][rr]);
      float ff = acc[1][rr] + bf2f(xgu[1][rr]);
      float gg = acc[2][rr] + bf2f(xgu[2][rr]);
      float oo = acc[3][rr] + bf2f(xgu[3][rr]);
      float cc = sigf(ff) * cv[rr] + sigf(ii) * tanhf_(gg);
      cv[rr] = cc;
      hbv[rr] = f2bf(sigf(oo) * tanhf_(cc));
    }
    // ---- store tagged h (fire-and-forget; store visibility IS the signal) + out ----
    unsigned tagw = (unsigned)(s + 1) & 0xffffu;
    #pragma unroll
    for (int rr = 0; rr < 4; rr++)
      __hip_atomic_store(hw + wb + rr * 8, ((unsigned)hbv[rr] << 16) | tagw,
                         __ATOMIC_RELAXED, __HIP_MEMORY_SCOPE_SYSTEM);
    bool evn = (jj & 1) == 0;
    #pragma unroll
    for (int rr = 0; rr < 4; rr++) {
      unsigned mine = (unsigned)hbv[rr];
      unsigned nb = (unsigned)__shfl_xor((int)mine, 1, 64);
      if (evn) {
        unsigned packed = mine | (nb << 16);
        int m = mbase + rr;
        *(unsigned*)&outL[((size_t)m * 512 + t) * 1024 + (d << 9) + j0 + jj] = packed;
      }
    }
    // rotate xg registers
    if (sl < 63) {
      #pragma unroll
      for (int rr = 0; rr < 4; rr++)
        #pragma unroll
        for (int qg = 0; qg < 4; qg++) xgu[qg][rr] = xgn[qg][rr];
    }
  }
  #pragma unroll
  for (int rr = 0; rr < 4; rr++) cstL[(size_t)d * 32768 + (mbase + rr) * 512 + j0 + jj] = cv[rr];
}

// ---------------- emissions ----------------
__global__ __launch_bounds__(256) void emis_kernel(const ushort_t* __restrict__ out1,
                                                   const ushort_t* __restrict__ wout_bf,
                                                   const float* __restrict__ b_out,
                                                   float* __restrict__ emis) {
  int tid = threadIdx.x, L = tid & 63, w = tid >> 6;
  int bm0 = blockIdx.x * 128;
  int q8 = L >> 4, ln = L & 15;
  floatx4 acc[2][2] = {};
  #pragma unroll 4
  for (int kb = 0; kb < 32; kb++) {
    short8 a0 = *(const short8*)&out1[(size_t)(bm0 + (w * 2 + 0) * 16 + ln) * 1024 + kb * 32 + q8 * 8];
    short8 a1 = *(const short8*)&out1[(size_t)(bm0 + (w * 2 + 1) * 16 + ln) * 1024 + kb * 32 + q8 * 8];
    #pragma unroll
    for (int nt = 0; nt < 2; nt++) {
      short8 bfr = *(const short8*)&wout_bf[((size_t)(nt * 32 + kb) * 64 + L) * 8];
      acc[0][nt] = __builtin_amdgcn_mfma_f32_16x16x32_bf16(a0, bfr, acc[0][nt], 0, 0, 0);
      acc[1][nt] = __builtin_amdgcn_mfma_f32_16x16x32_bf16(a1, bfr, acc[1][nt], 0, 0, 0);
    }
  }
  #pragma unroll
  for (int mt = 0; mt < 2; mt++) {
    #pragma unroll
    for (int nt = 0; nt < 2; nt++) {
      int n = nt * 16 + ln;
      float bv = b_out[n];
      #pragma unroll
      for (int rr = 0; rr < 4; rr++) {
        int m = bm0 + (w * 2 + mt) * 16 + q8 * 4 + rr;
        emis[(size_t)m * 32 + n] = acc[mt][nt][rr] + bv;
      }
    }
  }
}

// ---------------- CRF numerator ----------------
__global__ void num_kernel(const int* __restrict__ labels, const float* __restrict__ emis,
                           const float* __restrict__ trans, const float* __restrict__ cstart,
                           const float* __restrict__ cend, float* __restrict__ num) {
  int b = blockIdx.x, tid = threadIdx.x;
  float s = 0.f;
  for (int t = tid; t < 512; t += 64) {
    int tag = labels[b * 512 + t];
    s += emis[(size_t)(b * 512 + t) * 32 + tag];
    if (t < 511) s += trans[tag * 32 + labels[b * 512 + t + 1]];
  }
  #pragma unroll
  for (int off = 32; off > 0; off >>= 1) s += __shfl_xor(s, off, 64);
  if (tid == 0) num[b] = s + cstart[labels[b * 512]] + cend[labels[b * 512 + 511]];
}

// ---------------- CRF forward scan: linear-space inner product ----------------
__global__ __launch_bounds__(64) void fwd_kernel(const float* __restrict__ emis,
                                                 const float* __restrict__ trans,
                                                 const float* __restrict__ cstart,
                                                 const float* __restrict__ cend,
                                                 const float* __restrict__ num,
                                                 float* __restrict__ perb) {
  int b = blockIdx.x, tid = threadIdx.x, j = tid & 31;
  float Pj[32];
  #pragma unroll
  for (int i = 0; i < 32; i++) Pj[i] = __expf(trans[i * 32 + j]);
  float alpha = cstart[j] + emis[(size_t)(b * 512) * 32 + j];
  for (int t = 1; t < 512; t++) {
    float e = emis[(size_t)(b * 512 + t) * 32 + j];
    float M = alpha;
    #pragma unroll
    for (int off = 16; off > 0; off >>= 1) M = fmaxf(M, __shfl_xor(M, off, 32));
    float A = __expf(alpha - M);
    float s0 = 0.f, s1 = 0.f, s2 = 0.f, s3 = 0.f;
    #pragma unroll
    for (int i = 0; i < 32; i += 4) {
      s0 += __shfl(A, i, 32) * Pj[i];
      s1 += __shfl(A, i + 1, 32) * Pj[i + 1];
      s2 += __shfl(A, i + 2, 32) * Pj[i + 2];
      s3 += __shfl(A, i + 3, 32) * Pj[i + 3];
    }
    alpha = __logf((s0 + s1) + (s2 + s3)) + M + e;
  }
  float z = alpha + cend[j];
  float m2 = z;
  #pragma unroll
  for (int off = 16; off > 0; off >>= 1) m2 = fmaxf(m2, __shfl_xor(m2, off, 32));
  float s2 = __expf(z - m2);
  #pragma unroll
  for (int off = 16; off > 0; off >>= 1) s2 += __shfl_xor(s2, off, 32);
  if (tid == 0) perb[b] = num[b] - (__logf(s2) + m2);
}

__global__ void final_kernel(const float* __restrict__ perb, float* __restrict__ out) {
  int tid = threadIdx.x;
  float s = perb[tid];
  #pragma unroll
  for (int off = 32; off > 0; off >>= 1) s += __shfl_xor(s, off, 64);
  if (tid == 0) out[0] = -s;
}

// ---------------- host launch ----------------
extern "C" void kernel_launch(void* const* d_in, const int* in_sizes, int n_in,
                              void* d_out, int out_size, void* d_ws, size_t ws_size,
                              hipStream_t stream) {
  (void)in_sizes; (void)n_in; (void)out_size; (void)ws_size;
  const int* datas = (const int*)d_in[0];
  const int* labels = (const int*)d_in[1];
  const float* emb = (const float*)d_in[2];
  const float* w_ih0 = (const float*)d_in[3];
  const float* w_ih1 = (const float*)d_in[4];
  const float* w_hh = (const float*)d_in[5];
  const float* b_ih = (const float*)d_in[6];
  const float* b_hh = (const float*)d_in[7];
  const float* w_out = (const float*)d_in[8];
  const float* b_out = (const float*)d_in[9];
  const float* cstart = (const float*)d_in[10];
  const float* cend = (const float*)d_in[11];
  const float* ctrans = (const float*)d_in[12];

  char* ws = (char*)d_ws;
  ushort_t* x_bf = (ushort_t*)(ws + OFF_A);
  ushort_t* out1 = (ushort_t*)(ws + OFF_A);
  ushort_t* out0 = (ushort_t*)(ws + OFF_OUT0);
  ushort_t* xg0c = (ushort_t*)(ws + OFF_XG);
  ushort_t* xg1c = (ushort_t*)(ws + OFF_XG + 16777216);
  float* emis = (float*)(ws + OFF_XG);
  ushort_t* wih0_bf = (ushort_t*)(ws + OFF_WIH0);
  ushort_t* wih1_bf = (ushort_t*)(ws + OFF_WIH1);
  float* bias = (float*)(ws + OFF_BIAS);
  ushort_t* wout_bf = (ushort_t*)(ws + OFF_WOUT);
  unsigned* hc0 = (unsigned*)(ws + OFF_HC);   // layer0: [2 dir][2 parity][32768] u32
  unsigned* hc1 = hc0 + 131072;               // layer1
  float* cst0 = (float*)(ws + OFF_CST);
  float* cst1 = cst0 + 65536;
  float* numb = (float*)(ws + OFF_NUM);
  float* perb = (float*)(ws + OFF_PERB);

  // zero tagged h buffers (tag 0 = step-0 zeros), carry state, num/perb
  hipMemsetAsync(ws + OFF_HC, 0, OFF_END - OFF_HC, stream);

  prep_kernel<<<2048, 256, 0, stream>>>(w_ih0, w_ih1, b_ih, b_hh, w_out,
                                        wih0_bf, wih1_bf, bias, wout_bf);
  embed_kernel<<<8192, 256, 0, stream>>>(datas, emb, x_bf);

  // layer 0 (A = x_bf, K=512)
  for (int c = 0; c < 8; c++) {
    gemm_chunk<<<1024, 256, 0, stream>>>(x_bf, 512, wih0_bf, bias, xg0c, xg1c,
                                         c * 64, (7 - c) * 64);
    lstm_chunk<<<64, 256, 0, stream>>>(xg0c, xg1c, w_hh, hc0, cst0, out0, c);
  }
  // layer 1 (A = out0, K=1024)
  for (int c = 0; c < 8; c++) {
    gemm_chunk<<<1024, 256, 0, stream>>>(out0, 1024, wih1_bf, bias + 4096, xg0c, xg1c,
                                         c * 64, (7 - c) * 64);
    lstm_chunk<<<64, 256, 0, stream>>>(xg0c, xg1c, w_hh + 2097152, hc1, cst1, out1, c);
  }

  // emissions + CRF
  emis_kernel<<<256, 256, 0, stream>>>(out1, wout_bf, b_out, emis);
  num_kernel<<<64, 64, 0, stream>>>(labels, emis, ctrans, cstart, cend, numb);
  fwd_kernel<<<64, 64, 0, stream>>>(emis, ctrans, cstart, cend, numb, perb);
  final_kernel<<<1, 64, 0, stream>>>(perb, (float*)d_out);
}